// Round 10
// baseline (371.967 us; speedup 1.0000x reference)
//
#include <hip/hip_runtime.h>
#include <hip/hip_bf16.h>

// EnhancedSpatioTemporalLayer forward, round 10.
// AB (per (b,t)): conv -> small GEMM -> Z[b][o][t][m] bf16 (m contiguous).
// C  (per (b, o, t32)): Z staged via global_load_lds (swizzled source, linear
//    LDS); K-loop is DEPTH-2 SOFTWARE-PIPELINED (cf/zf fragment prefetch) so
//    L2 latency hides under MFMA issue. Full-line t-major stores.

#define Bx   16
#define FINx 3
#define Nx   170
#define Tx   288
#define Hx   64
#define Ox   64
#define Kx   3
#define NP   192            // padded n/m (12 x 16)
#define TMW  72             // sTm row stride (bf16): 144B -> 2-way banks
#define NBT  (Bx * Tx)      // 4608
#define ZROW 1152           // C: LDS Z row stride bytes (576 bf16, LINEAR)

#define CHEBF_ELEMS (Kx * 6 * 12 * 64 * 8)   // 110592: [sg=k*6+s][nt][lane][8]
#define THF_ELEMS   (Kx * 2 * 4 * 64 * 8)    // 12288:  [k][s][ot][lane][8]
#define ZELEMS ((size_t)Bx * Ox * Tx * 576)  // 169,869,312 (~340 MB bf16)
#define ZBYTES (ZELEMS * 2)

typedef __attribute__((ext_vector_type(8))) short bf16x8;
typedef __attribute__((ext_vector_type(4))) short bf16x4;
typedef __attribute__((ext_vector_type(4))) float f32x4;

__device__ __align__(16) __hip_bfloat16 g_chebfrag[CHEBF_ELEMS];
__device__ __align__(16) __hip_bfloat16 g_thfrag[THF_ELEMS];
__device__ __align__(16) __hip_bfloat16 g_Z[ZELEMS];   // fallback Z buffer

static __device__ __forceinline__ short f2bf(float f) {
    __hip_bfloat16 h = __float2bfloat16(f);
    return *reinterpret_cast<short*>(&h);
}

// g_chebfrag[((sg*12+nt)*64+lane)*8+j] = cheb_k[n][m], sg = k*6+s,
//     n = nt*16 + (lane&15), m = s*32 + (lane>>4)*8 + j   (0 outside 170)
// g_thfrag [(((k*2+s)*4+ot)*64+lane)*8+j] = theta[k][c][o],
//     o = ot*16 + (lane&15), c = s*32 + (lane>>4)*8 + j
__global__ __launch_bounds__(512)
void precompute_frag(const float* __restrict__ cheb, const float* __restrict__ theta) {
    int idx = blockIdx.x * 512 + threadIdx.x;
    if (idx < CHEBF_ELEMS) {
        int j = idx & 7, lane = (idx >> 3) & 63, rest = idx >> 9;
        int nt = rest % 12; rest /= 12;
        int s = rest % 6, k = rest / 6;
        int n = nt * 16 + (lane & 15);
        int m = s * 32 + (lane >> 4) * 8 + j;
        float v = (n < Nx && m < Nx) ? cheb[(k * Nx + n) * Nx + m] : 0.f;
        g_chebfrag[idx] = __float2bfloat16(v);
    } else if (idx < CHEBF_ELEMS + THF_ELEMS) {
        int jdx = idx - CHEBF_ELEMS;
        int j = jdx & 7, lane = (jdx >> 3) & 63, rest = jdx >> 9;
        int ot = rest % 4; rest /= 4;
        int s = rest % 2, k = rest / 2;
        int o = ot * 16 + (lane & 15);
        int c = s * 32 + (lane >> 4) * 8 + j;
        g_thfrag[jdx] = __float2bfloat16(theta[(k * Hx + c) * Ox + o]);
    }
}

// ---------------- AB: conv + theta GEMM -> Z[b][o][t][m] ----------------
__global__ __launch_bounds__(256, 4)
void stgcn_ab(const float* __restrict__ x,
              const float* __restrict__ conv_w,
              const float* __restrict__ conv_b,
              __hip_bfloat16* __restrict__ Z) {
    __shared__ __align__(16) __hip_bfloat16 sTm[NP * TMW];  // 27.6 KB
    __shared__ float sXs[Nx * 9];                           // 6.1 KB

    const int tid = threadIdx.x;
    const int vid = (blockIdx.x & 7) * 576 + (blockIdx.x >> 3);
    const int b  = vid / Tx;
    const int t0 = vid % Tx;

    for (int idx = tid; idx < Nx * 9; idx += 256) {
        int n = idx / 9, r = idx % 9, f = r / 3, j = r % 3;
        int tt = t0 - 1 + j;
        float v = 0.f;
        if (tt >= 0 && tt < Tx) v = x[((b * FINx + f) * Nx + n) * Tx + tt];
        sXs[idx] = v;
    }
    const int cc = tid & 63;
    float wreg[9];
#pragma unroll
    for (int r = 0; r < 9; ++r) wreg[r] = conv_w[cc * 9 + r];
    const float bias = conv_b[cc];
    __syncthreads();

    for (int m = (tid >> 6); m < Nx; m += 4) {
        float acc = bias;
#pragma unroll
        for (int r = 0; r < 9; ++r) acc += sXs[m * 9 + r] * wreg[r];
        sTm[m * TMW + cc] = __float2bfloat16(fmaxf(acc, 0.f));
    }
    for (int idx = tid; idx < (NP - Nx) * 64; idx += 256) {
        int m = Nx + idx / 64, c = idx % 64;
        sTm[m * TMW + c] = __float2bfloat16(0.f);
    }
    __syncthreads();

    const int lane = tid & 63;
    const int w    = tid >> 6;     // 0..3: m-tiles w*3..w*3+2
    const int l16  = lane & 15;
    const int lk   = lane >> 4;
    __hip_bfloat16* zb = Z + ((size_t)(b * Ox) * Tx + t0) * 576;

    for (int k = 0; k < Kx; ++k) {
        f32x4 accs[3][4];
#pragma unroll
        for (int j = 0; j < 3; ++j)
#pragma unroll
            for (int u = 0; u < 4; ++u) accs[j][u] = (f32x4)0.f;

#pragma unroll
        for (int s = 0; s < 2; ++s) {
            bf16x8 afr[3], bfr[4];
#pragma unroll
            for (int j = 0; j < 3; ++j)
                afr[j] = *(const bf16x8*)((const char*)sTm +
                         ((w * 3 + j) * 16 + l16) * (TMW * 2) + s * 64 + lk * 16);
#pragma unroll
            for (int u = 0; u < 4; ++u)
                bfr[u] = *(const bf16x8*)(&g_thfrag[(((k * 2 + s) * 4 + u) * 64 + lane) * 8]);
            // mfma(Tm, theta): D col(l16) = o, row(lk*4+r) = m (4 consecutive)
#pragma unroll
            for (int j = 0; j < 3; ++j)
#pragma unroll
                for (int u = 0; u < 4; ++u)
                    accs[j][u] = __builtin_amdgcn_mfma_f32_16x16x32_bf16(afr[j], bfr[u], accs[j][u], 0, 0, 0);
        }
#pragma unroll
        for (int j = 0; j < 3; ++j)
#pragma unroll
            for (int u = 0; u < 4; ++u) {
                int o  = u * 16 + l16;
                int mm = k * NP + (w * 3 + j) * 16 + lk * 4;
                bf16x4 v;
#pragma unroll
                for (int r = 0; r < 4; ++r) v[r] = f2bf(accs[j][u][r]);
                *(bf16x4*)(zb + (size_t)o * (Tx * 576) + mm) = v;
            }
    }
}

// ---------------- C: pipelined big GEMM + epilogue ----------------
// block: (b, o, t32). 256 thr (4 waves). wave w owns n-tiles w*3..w*3+2.
// Depth-2 rotating prefetch of cf (global/L2) and zf (LDS) fragments.
__global__ __launch_bounds__(256, 4)
void stgcn_c5(const __hip_bfloat16* __restrict__ Z,
              const float* __restrict__ x,
              const float* __restrict__ res_w,
              const float* __restrict__ res_b,
              float* __restrict__ out) {
    __shared__ __align__(16) char sZb[32 * ZROW];   // 36,864 B, linear

    const int tid = threadIdx.x;
    const int vid = (blockIdx.x & 7) * 1152 + (blockIdx.x >> 3);  // 9216 = 8*1152
    const int b   = vid / 576;
    const int rem = vid % 576;
    const int tt  = rem / 64;      // t-tile of 32 (0..8)
    const int o   = rem % 64;
    const int tbase = tt * 32;

    const int lane = tid & 63;
    const int w    = tid >> 6;

    // ---- stage Z slice [32 t][576 m] via global_load_lds, swizzled source ----
    {
        const char* zsrc = (const char*)(Z + ((size_t)(b * Ox + o) * Tx + tbase) * 576);
#pragma unroll
        for (int i = 0; i < 9; ++i) {
            int chunk = (w * 9 + i) * 1024;          // wave-uniform
            int off   = chunk + lane * 16;           // linear LDS offset this lane fills
            int row   = off / ZROW;
            int soff  = off ^ ((row & 7) << 4);      // involution, stays in-row & in-line
            __builtin_amdgcn_global_load_lds(zsrc + soff, sZb + chunk, 16, 0, 0);
        }
    }
    __syncthreads();

    const int l16  = lane & 15;
    const int lk   = lane >> 4;
    const int zxor = (l16 & 7) << 4;    // row = ti*16+l16 -> row&7 == l16&7

    // cf addr for (s, ni): cfbase + s*12288 + ni*1024
    const char* cfbase = (const char*)g_chebfrag + ((size_t)(w * 3) * 64 + lane) * 16;
    const int zy0 = l16 * ZROW + lk * 16;          // ti=0 row base
    const int zy1 = (16 + l16) * ZROW + lk * 16;   // ti=1 row base

#define LDCF(dst, s)                                                        \
    do {                                                                    \
        dst[0] = *(const bf16x8*)(cfbase + (s) * 12288);                    \
        dst[1] = *(const bf16x8*)(cfbase + (s) * 12288 + 1024);             \
        dst[2] = *(const bf16x8*)(cfbase + (s) * 12288 + 2048);             \
    } while (0)
#define LDZF(dst, s)                                                        \
    do {                                                                    \
        dst[0] = *(const bf16x8*)(sZb + ((zy0 + (s) * 64) ^ zxor));         \
        dst[1] = *(const bf16x8*)(sZb + ((zy1 + (s) * 64) ^ zxor));         \
    } while (0)
#define MFMA6(cf, zf)                                                       \
    do {                                                                    \
        _Pragma("unroll")                                                   \
        for (int ni = 0; ni < 3; ++ni)                                      \
            _Pragma("unroll")                                               \
            for (int ti = 0; ti < 2; ++ti)                                  \
                acc[ni][ti] = __builtin_amdgcn_mfma_f32_16x16x32_bf16(      \
                    cf[ni], zf[ti], acc[ni][ti], 0, 0, 0);                  \
    } while (0)

    f32x4 acc[3][2];
#pragma unroll
    for (int ni = 0; ni < 3; ++ni)
#pragma unroll
        for (int ti = 0; ti < 2; ++ti) acc[ni][ti] = (f32x4)0.f;

    bf16x8 cf0[3], zf0[2], cf1[3], zf1[2];
    LDCF(cf0, 0); LDZF(zf0, 0);
    LDCF(cf1, 1); LDZF(zf1, 1);

#pragma unroll
    for (int sp = 0; sp < 9; ++sp) {
        bf16x8 ncf0[3], nzf0[2], ncf1[3], nzf1[2];
        if (sp < 8) { LDCF(ncf0, 2 * sp + 2); LDZF(nzf0, 2 * sp + 2); }
        MFMA6(cf0, zf0);
        if (sp < 8) { LDCF(ncf1, 2 * sp + 3); LDZF(nzf1, 2 * sp + 3); }
        MFMA6(cf1, zf1);
        if (sp < 8) {
#pragma unroll
            for (int i = 0; i < 3; ++i) { cf0[i] = ncf0[i]; cf1[i] = ncf1[i]; }
#pragma unroll
            for (int i = 0; i < 2; ++i) { zf0[i] = nzf0[i]; zf1[i] = nzf1[i]; }
        }
    }
#undef LDCF
#undef LDZF
#undef MFMA6

    // ---- epilogue: relu + residual, t-major full-line stores ----
    const float rw0 = res_w[o * 3 + 0], rw1 = res_w[o * 3 + 1], rw2 = res_w[o * 3 + 2];
    const float rb  = res_b[o];
    float* ob = out + ((size_t)(b * Ox + o) * Nx) * Tx;
    const float* xb = x + (size_t)(b * FINx) * Nx * Tx;

#pragma unroll
    for (int ni = 0; ni < 3; ++ni) {
#pragma unroll
        for (int r = 0; r < 4; ++r) {
            const int n = (w * 3 + ni) * 16 + lk * 4 + r;
            if (n < Nx) {
#pragma unroll
                for (int ti = 0; ti < 2; ++ti) {
                    const int t = tbase + ti * 16 + l16;
                    float xf0 = xb[(0 * Nx + n) * Tx + t];
                    float xf1 = xb[(1 * Nx + n) * Tx + t];
                    float xf2 = xb[(2 * Nx + n) * Tx + t];
                    float resv = rb + xf0 * rw0 + xf1 * rw1 + xf2 * rw2;
                    ob[n * Tx + t] = fmaxf(acc[ni][ti][r], 0.f) + resv;
                }
            }
        }
    }
}

extern "C" void kernel_launch(void* const* d_in, const int* in_sizes, int n_in,
                              void* d_out, int out_size, void* d_ws, size_t ws_size,
                              hipStream_t stream) {
    const float* x      = (const float*)d_in[0];
    const float* cheb   = (const float*)d_in[2];
    const float* conv_w = (const float*)d_in[3];
    const float* conv_b = (const float*)d_in[4];
    const float* theta  = (const float*)d_in[5];
    const float* res_w  = (const float*)d_in[6];
    const float* res_b  = (const float*)d_in[7];
    float* out = (float*)d_out;

    __hip_bfloat16* zptr;
    if (ws_size >= ZBYTES) {
        zptr = (__hip_bfloat16*)d_ws;
    } else {
        void* sym = nullptr;
        hipGetSymbolAddress(&sym, HIP_SYMBOL(g_Z));
        zptr = (__hip_bfloat16*)sym;
    }

    int pre_elems = CHEBF_ELEMS + THF_ELEMS;
    hipLaunchKernelGGL(precompute_frag, dim3((pre_elems + 511) / 512), dim3(512), 0, stream,
                       cheb, theta);
    hipLaunchKernelGGL(stgcn_ab, dim3(NBT), dim3(256), 0, stream,
                       x, conv_w, conv_b, zptr);
    hipLaunchKernelGGL(stgcn_c5, dim3(9216), dim3(256), 0, stream,
                       zptr, x, res_w, res_b, out);
}

// Round 11
// 288.354 us; speedup vs baseline: 1.2900x; 1.2900x over previous
//
#include <hip/hip_runtime.h>
#include <hip/hip_bf16.h>

// EnhancedSpatioTemporalLayer fused forward, round 11.
// Round-5 fused structure (per-(b,t) block, 512 thr, 2 blocks/CU) + T0=I
// shortcut: k=0's big GEMM (cheb_0 = identity) replaced by a direct LDS fold
// of Z_0 into the accumulator. Big-GEMM K: 576 -> 384.

#define Bx   16
#define FINx 3
#define Nx   170
#define Tx   288
#define Hx   64
#define Ox   64
#define Kx   3
#define NP   192            // padded n/m (12 x 16)
#define TMW  72             // sTm row stride (bf16): 144B -> 2-way banks
#define ZW   200            // sZk row stride (bf16): 400B -> 2-way banks
#define NBT  (Bx * Tx)      // 4608

#define CHEBF_ELEMS (Kx * 6 * 12 * 64 * 8)   // 110592: [sg=k*6+s][nt][lane][8]
#define THF_ELEMS   (Kx * 2 * 4 * 64 * 8)    // 12288:  [k][s][ot][lane][8]

typedef __attribute__((ext_vector_type(8))) short bf16x8;
typedef __attribute__((ext_vector_type(4))) short bf16x4;
typedef __attribute__((ext_vector_type(4))) float f32x4;

__device__ __align__(16) __hip_bfloat16 g_chebfrag[CHEBF_ELEMS];
__device__ __align__(16) __hip_bfloat16 g_thfrag[THF_ELEMS];

static __device__ __forceinline__ short f2bf(float f) {
    __hip_bfloat16 h = __float2bfloat16(f);
    return *reinterpret_cast<short*>(&h);
}

// g_chebfrag[((sg*12+nt)*64+lane)*8+j] = cheb_k[n][m], sg = k*6+s,
//     n = nt*16 + (lane&15), m = s*32 + (lane>>4)*8 + j   (0 outside 170)
// g_thfrag [(((k*2+s)*4+ot)*64+lane)*8+j] = theta[k][c][o],
//     o = ot*16 + (lane&15), c = s*32 + (lane>>4)*8 + j
__global__ __launch_bounds__(512)
void precompute_frag(const float* __restrict__ cheb, const float* __restrict__ theta) {
    int idx = blockIdx.x * 512 + threadIdx.x;
    if (idx < CHEBF_ELEMS) {
        int j = idx & 7, lane = (idx >> 3) & 63, rest = idx >> 9;
        int nt = rest % 12; rest /= 12;
        int s = rest % 6, k = rest / 6;
        int n = nt * 16 + (lane & 15);
        int m = s * 32 + (lane >> 4) * 8 + j;
        float v = (n < Nx && m < Nx) ? cheb[(k * Nx + n) * Nx + m] : 0.f;
        g_chebfrag[idx] = __float2bfloat16(v);
    } else if (idx < CHEBF_ELEMS + THF_ELEMS) {
        int jdx = idx - CHEBF_ELEMS;
        int j = jdx & 7, lane = (jdx >> 3) & 63, rest = jdx >> 9;
        int ot = rest % 4; rest /= 4;
        int s = rest % 2, k = rest / 2;
        int o = ot * 16 + (lane & 15);
        int c = s * 32 + (lane >> 4) * 8 + j;
        g_thfrag[jdx] = __float2bfloat16(theta[(k * Hx + c) * Ox + o]);
    }
}

__global__ __launch_bounds__(512, 4)
void stgcn_fused4(const float* __restrict__ x,
                  const float* __restrict__ conv_w,
                  const float* __restrict__ conv_b,
                  const float* __restrict__ res_w,
                  const float* __restrict__ res_b,
                  float* __restrict__ out) {
    __shared__ __align__(16) __hip_bfloat16 sTm[NP * TMW];  // 27.6 KB
    __shared__ __align__(16) __hip_bfloat16 sZk[Ox * ZW];   // 25.6 KB
    __shared__ float sXs[Nx * 9];                           // 6.1 KB
    __shared__ float sResW[Ox * 3];
    __shared__ float sResB[Ox];

    const int tid = threadIdx.x;
    const int vid = (blockIdx.x & 7) * 576 + (blockIdx.x >> 3);  // XCD-chunked swizzle
    const int b  = vid / Tx;
    const int t0 = vid % Tx;

    // ---- stage x slice + residual params ----
    for (int idx = tid; idx < Nx * 9; idx += 512) {
        int n = idx / 9, r = idx % 9, f = r / 3, j = r % 3;
        int tt = t0 - 1 + j;
        float v = 0.f;
        if (tt >= 0 && tt < Tx) v = x[((b * FINx + f) * Nx + n) * Tx + tt];
        sXs[idx] = v;
    }
    for (int idx = tid; idx < Ox * 3; idx += 512) sResW[idx] = res_w[idx];
    for (int idx = tid; idx < Ox;     idx += 512) sResB[idx] = res_b[idx];

    const int cc = tid & 63;
    float wreg[9];
#pragma unroll
    for (int r = 0; r < 9; ++r) wreg[r] = conv_w[cc * 9 + r];
    const float bias = conv_b[cc];

    __syncthreads();

    // ---- temporal conv + ReLU -> bf16 sTm[m][cc]; zero pad rows ----
    for (int m = (tid >> 6); m < Nx; m += 8) {
        float acc = bias;
#pragma unroll
        for (int r = 0; r < 9; ++r) acc += sXs[m * 9 + r] * wreg[r];
        sTm[m * TMW + cc] = __float2bfloat16(fmaxf(acc, 0.f));
    }
    for (int idx = tid; idx < (NP - Nx) * 64; idx += 512) {
        int m = Nx + idx / 64, c = idx % 64;
        sTm[m * TMW + c] = __float2bfloat16(0.f);
    }

    const int lane = tid & 63;
    const int w    = tid >> 6;
    const int l16  = lane & 15;
    const int lk   = lane >> 4;

    const int mg = w & 3;        // small GEMM: m-tiles mg*3+j  (j=0..2)
    const int og = w >> 2;       // small GEMM: o-tiles og*2+u  (u=0..1)
    const int wr = w & 1;        // big GEMM:   o-tiles wr*2+oi (oi=0..1)
    const int wc = w >> 1;       // big GEMM:   n-tiles wc*3+nj (nj=0..2)

    f32x4 accb[2][3];            // persistent GT accumulator
#pragma unroll
    for (int oi = 0; oi < 2; ++oi)
#pragma unroll
        for (int nj = 0; nj < 3; ++nj) accb[oi][nj] = (f32x4)0.f;

    for (int k = 0; k < Kx; ++k) {
        __syncthreads();   // k=0: conv done; k>0: sZk consumers of k-1 done

        // ---- small GEMM: Z_k[m][o] = Tm[192x64] @ theta_k[64x64] ----
        f32x4 accs[3][2];
#pragma unroll
        for (int j = 0; j < 3; ++j)
#pragma unroll
            for (int u = 0; u < 2; ++u) accs[j][u] = (f32x4)0.f;

#pragma unroll
        for (int s = 0; s < 2; ++s) {
            bf16x8 afr[3], bfr[2];
#pragma unroll
            for (int j = 0; j < 3; ++j)
                afr[j] = *(const bf16x8*)((const char*)sTm +
                         ((mg * 3 + j) * 16 + l16) * (TMW * 2) + s * 64 + lk * 16);
#pragma unroll
            for (int u = 0; u < 2; ++u)
                bfr[u] = *(const bf16x8*)(&g_thfrag[
                         ((((k * 2 + s) * 4) + og * 2 + u) * 64 + lane) * 8]);
#pragma unroll
            for (int j = 0; j < 3; ++j)
#pragma unroll
                for (int u = 0; u < 2; ++u)
                    accs[j][u] = __builtin_amdgcn_mfma_f32_16x16x32_bf16(afr[j], bfr[u], accs[j][u], 0, 0, 0);
        }
        // store transposed slice: sZk[o][m]  (D: col o = tile+l16, rows m = lk*4+r)
#pragma unroll
        for (int j = 0; j < 3; ++j)
#pragma unroll
            for (int u = 0; u < 2; ++u) {
                int o  = (og * 2 + u) * 16 + l16;
                int m0 = (mg * 3 + j) * 16 + lk * 4;
                bf16x4 v;
#pragma unroll
                for (int r = 0; r < 4; ++r) v[r] = f2bf(accs[j][u][r]);
                *(bf16x4*)((char*)sZk + o * (ZW * 2) + m0 * 2) = v;
            }
        __syncthreads();

        if (k == 0) {
            // ---- T0 = I shortcut: G[o][n] += Z_0[n][o] (direct LDS fold) ----
#pragma unroll
            for (int oi = 0; oi < 2; ++oi)
#pragma unroll
                for (int nj = 0; nj < 3; ++nj) {
                    int n = (wc * 3 + nj) * 16 + l16;
#pragma unroll
                    for (int r = 0; r < 4; ++r) {
                        int o = (wr * 2 + oi) * 16 + lk * 4 + r;
                        accb[oi][nj][r] += __bfloat162float(sZk[o * ZW + n]);
                    }
                }
        } else {
            // ---- big GEMM partial: GT[o][n] += Z_k^T[o][m] @ cheb_k[n][m] ----
#pragma unroll
            for (int s = 0; s < 6; ++s) {
                bf16x8 afr2[2], bfr2[3];
#pragma unroll
                for (int oi = 0; oi < 2; ++oi)
                    afr2[oi] = *(const bf16x8*)((const char*)sZk +
                               ((wr * 2 + oi) * 16 + l16) * (ZW * 2) + s * 64 + lk * 16);
#pragma unroll
                for (int nj = 0; nj < 3; ++nj)
                    bfr2[nj] = *(const bf16x8*)(&g_chebfrag[
                               ((((k * 6 + s) * 12) + wc * 3 + nj) * 64 + lane) * 8]);
#pragma unroll
                for (int oi = 0; oi < 2; ++oi)
#pragma unroll
                    for (int nj = 0; nj < 3; ++nj)
                        accb[oi][nj] = __builtin_amdgcn_mfma_f32_16x16x32_bf16(afr2[oi], bfr2[nj], accb[oi][nj], 0, 0, 0);
            }
        }
    }

    // ---- epilogue: relu + residual, scatter store ----
#pragma unroll
    for (int nj = 0; nj < 3; ++nj) {
        int n = (wc * 3 + nj) * 16 + l16;
        if (n < Nx) {
            float xf0 = sXs[n * 9 + 1];
            float xf1 = sXs[n * 9 + 4];
            float xf2 = sXs[n * 9 + 7];
#pragma unroll
            for (int oi = 0; oi < 2; ++oi) {
#pragma unroll
                for (int r = 0; r < 4; ++r) {
                    int o = (wr * 2 + oi) * 16 + lk * 4 + r;
                    float resv = sResB[o] + xf0 * sResW[o * 3 + 0]
                                          + xf1 * sResW[o * 3 + 1]
                                          + xf2 * sResW[o * 3 + 2];
                    out[((b * Ox + o) * Nx + n) * Tx + t0] =
                        fmaxf(accb[oi][nj][r], 0.f) + resv;
                }
            }
        }
    }
}

extern "C" void kernel_launch(void* const* d_in, const int* in_sizes, int n_in,
                              void* d_out, int out_size, void* d_ws, size_t ws_size,
                              hipStream_t stream) {
    const float* x      = (const float*)d_in[0];
    const float* cheb   = (const float*)d_in[2];
    const float* conv_w = (const float*)d_in[3];
    const float* conv_b = (const float*)d_in[4];
    const float* theta  = (const float*)d_in[5];
    const float* res_w  = (const float*)d_in[6];
    const float* res_b  = (const float*)d_in[7];
    float* out = (float*)d_out;

    int pre_elems = CHEBF_ELEMS + THF_ELEMS;
    hipLaunchKernelGGL(precompute_frag, dim3((pre_elems + 511) / 512), dim3(512), 0, stream,
                       cheb, theta);
    hipLaunchKernelGGL(stgcn_fused4, dim3(NBT), dim3(512), 0, stream,
                       x, conv_w, conv_b, res_w, res_b, out);
}

// Round 12
// 279.010 us; speedup vs baseline: 1.3332x; 1.0335x over previous
//
#include <hip/hip_runtime.h>
#include <hip/hip_bf16.h>

// EnhancedSpatioTemporalLayer fused forward, round 12.
// Per-(b,t) block, 512 thr, 2 blocks/CU.
// conv via MFMA (bias folded as K-slot 9) -> k=0 cheb-identity fully
// in-register (accb += mfma(theta0, Tm)) -> k=1,2: small GEMM -> sZk ->
// big GEMM vs frag-order cheb -> relu+residual epilogue.

#define Bx   16
#define FINx 3
#define Nx   170
#define Tx   288
#define Hx   64
#define Ox   64
#define Kx   3
#define NP   192            // padded n/m (12 x 16)
#define TMW  72             // sTm row stride (bf16): 144B -> 2-way banks
#define ZW   200            // sZk row stride (bf16): 400B -> 2-way banks
#define XSW  12             // sXs row stride (f32): 48B, float4-aligned
#define NBT  (Bx * Tx)      // 4608

#define CHEBF_ELEMS (Kx * 6 * 12 * 64 * 8)   // 110592: [sg=k*6+s][nt][lane][8]
#define THF_ELEMS   (Kx * 2 * 4 * 64 * 8)    // 12288:  [k][s][ot][lane][8]
#define WF_ELEMS    (4 * 64 * 8)             // 2048:   [ct][lane][8]

typedef __attribute__((ext_vector_type(8))) short bf16x8;
typedef __attribute__((ext_vector_type(4))) short bf16x4;
typedef __attribute__((ext_vector_type(4))) float f32x4;

__device__ __align__(16) __hip_bfloat16 g_chebfrag[CHEBF_ELEMS];
__device__ __align__(16) __hip_bfloat16 g_thfrag[THF_ELEMS];
__device__ __align__(16) __hip_bfloat16 g_wfrag[WF_ELEMS];

static __device__ __forceinline__ short f2bf(float f) {
    __hip_bfloat16 h = __float2bfloat16(f);
    return *reinterpret_cast<short*>(&h);
}

// g_chebfrag[((sg*12+nt)*64+lane)*8+j] = cheb_k[n][m], sg = k*6+s,
//     n = nt*16 + (lane&15), m = s*32 + (lane>>4)*8 + j   (0 outside 170)
// g_thfrag [(((k*2+s)*4+ot)*64+lane)*8+j] = theta[k][c][o],
//     o = ot*16 + (lane&15), c = s*32 + (lane>>4)*8 + j
// g_wfrag  [(ct*64+lane)*8+j]: c = ct*16+(lane&15), slot = (lane>>4)*8+j:
//     slot<9 -> conv_w[c*9+slot]; slot==9 -> conv_b[c]; else 0
__global__ __launch_bounds__(512)
void precompute_frag(const float* __restrict__ cheb, const float* __restrict__ theta,
                     const float* __restrict__ conv_w, const float* __restrict__ conv_b) {
    int idx = blockIdx.x * 512 + threadIdx.x;
    if (idx < CHEBF_ELEMS) {
        int j = idx & 7, lane = (idx >> 3) & 63, rest = idx >> 9;
        int nt = rest % 12; rest /= 12;
        int s = rest % 6, k = rest / 6;
        int n = nt * 16 + (lane & 15);
        int m = s * 32 + (lane >> 4) * 8 + j;
        float v = (n < Nx && m < Nx) ? cheb[(k * Nx + n) * Nx + m] : 0.f;
        g_chebfrag[idx] = __float2bfloat16(v);
    } else if (idx < CHEBF_ELEMS + THF_ELEMS) {
        int jdx = idx - CHEBF_ELEMS;
        int j = jdx & 7, lane = (jdx >> 3) & 63, rest = jdx >> 9;
        int ot = rest % 4; rest /= 4;
        int s = rest % 2, k = rest / 2;
        int o = ot * 16 + (lane & 15);
        int c = s * 32 + (lane >> 4) * 8 + j;
        g_thfrag[jdx] = __float2bfloat16(theta[(k * Hx + c) * Ox + o]);
    } else if (idx < CHEBF_ELEMS + THF_ELEMS + WF_ELEMS) {
        int jdx = idx - CHEBF_ELEMS - THF_ELEMS;
        int j = jdx & 7, lane = (jdx >> 3) & 63, ct = jdx >> 9;
        int c = ct * 16 + (lane & 15);
        int slot = (lane >> 4) * 8 + j;
        float v = 0.f;
        if (slot < 9) v = conv_w[c * 9 + slot];
        else if (slot == 9) v = conv_b[c];
        g_wfrag[jdx] = __float2bfloat16(v);
    }
}

__global__ __launch_bounds__(512, 4)
void stgcn_fused5(const float* __restrict__ x,
                  const float* __restrict__ res_w,
                  const float* __restrict__ res_b,
                  float* __restrict__ out) {
    __shared__ __align__(16) __hip_bfloat16 sTm[NP * TMW];  // 27.6 KB
    __shared__ __align__(16) __hip_bfloat16 sZk[Ox * ZW];   // 25.6 KB
    __shared__ __align__(16) float sXs[NP * XSW];           // 9.2 KB
    __shared__ float sResW[Ox * 3];
    __shared__ float sResB[Ox];

    const int tid = threadIdx.x;
    const int vid = (blockIdx.x & 7) * 576 + (blockIdx.x >> 3);  // XCD-chunked swizzle
    const int b  = vid / Tx;
    const int t0 = vid % Tx;

    // ---- stage x slice [192][12] (zeros outside 170 rows / 9 cols) ----
    for (int idx = tid; idx < NP * XSW; idx += 512) {
        int n = idx / XSW, r = idx % XSW;
        float v = 0.f;
        if (n < Nx && r < 9) {
            int f = r / 3, j = r % 3;
            int tt = t0 - 1 + j;
            if (tt >= 0 && tt < Tx) v = x[((b * FINx + f) * Nx + n) * Tx + tt];
        }
        sXs[idx] = v;
    }
    for (int idx = tid; idx < Ox * 3; idx += 512) sResW[idx] = res_w[idx];
    for (int idx = tid; idx < Ox;     idx += 512) sResB[idx] = res_b[idx];

    const int lane = tid & 63;
    const int w    = tid >> 6;
    const int l16  = lane & 15;
    const int lk   = lane >> 4;

    const int mg = w & 3;        // conv/small GEMM: m-tiles mg*3+j (j=0..2)
    const int og = w >> 2;       // conv/small GEMM: o/c-tiles og*2+u (u=0..1)
    const int wr = w & 1;        // big GEMM: o-tiles wr*2+oi (oi=0..1)
    const int wc = w >> 1;       // big GEMM: n-tiles wc*3+nj (nj=0..2)

    __syncthreads();

    // ---- conv via MFMA: Tm[m][c] = relu(Xp @ Wf) (bias in slot 9) ----
    {
        bf16x8 wfr[2], xfr[3];
#pragma unroll
        for (int u = 0; u < 2; ++u)
            wfr[u] = *(const bf16x8*)(&g_wfrag[((og * 2 + u) * 64 + lane) * 8]);
#pragma unroll
        for (int j = 0; j < 3; ++j) {
            int m = (mg * 3 + j) * 16 + l16;
            bf16x8 xf;
#pragma unroll
            for (int q = 0; q < 8; ++q) xf[q] = 0;
            if (lk == 0) {
                float4 a0 = *(const float4*)(&sXs[m * XSW + 0]);
                float4 a1 = *(const float4*)(&sXs[m * XSW + 4]);
                xf[0] = f2bf(a0.x); xf[1] = f2bf(a0.y);
                xf[2] = f2bf(a0.z); xf[3] = f2bf(a0.w);
                xf[4] = f2bf(a1.x); xf[5] = f2bf(a1.y);
                xf[6] = f2bf(a1.z); xf[7] = f2bf(a1.w);
            } else if (lk == 1) {
                xf[0] = f2bf(sXs[m * XSW + 8]);
                xf[1] = f2bf(1.0f);           // slot 9 = bias
            }
            xfr[j] = xf;
        }
#pragma unroll
        for (int j = 0; j < 3; ++j)
#pragma unroll
            for (int u = 0; u < 2; ++u) {
                f32x4 tacc = (f32x4)0.f;
                tacc = __builtin_amdgcn_mfma_f32_16x16x32_bf16(wfr[u], xfr[j], tacc, 0, 0, 0);
                // D: col(l16) = m, row(lk*4+r) = c -> bf16x4 store
                int m  = (mg * 3 + j) * 16 + l16;
                int c0 = (og * 2 + u) * 16 + lk * 4;
                bf16x4 v;
#pragma unroll
                for (int r = 0; r < 4; ++r) v[r] = f2bf(fmaxf(tacc[r], 0.f));
                *(bf16x4*)((char*)sTm + m * (TMW * 2) + c0 * 2) = v;
            }
    }
    __syncthreads();

    f32x4 accb[2][3];            // persistent GT accumulator [oi][nj]
#pragma unroll
    for (int oi = 0; oi < 2; ++oi)
#pragma unroll
        for (int nj = 0; nj < 3; ++nj) accb[oi][nj] = (f32x4)0.f;

    // ---- k=0 (cheb_0 = I): accb += mfma(theta0(o-rows), Tm(n-rows)) ----
#pragma unroll
    for (int s = 0; s < 2; ++s) {
        bf16x8 tf[2], nf[3];
#pragma unroll
        for (int oi = 0; oi < 2; ++oi)
            tf[oi] = *(const bf16x8*)(&g_thfrag[((s * 4 + wr * 2 + oi) * 64 + lane) * 8]);
#pragma unroll
        for (int nj = 0; nj < 3; ++nj)
            nf[nj] = *(const bf16x8*)((const char*)sTm +
                     ((wc * 3 + nj) * 16 + l16) * (TMW * 2) + s * 64 + lk * 16);
#pragma unroll
        for (int oi = 0; oi < 2; ++oi)
#pragma unroll
            for (int nj = 0; nj < 3; ++nj)
                accb[oi][nj] = __builtin_amdgcn_mfma_f32_16x16x32_bf16(tf[oi], nf[nj], accb[oi][nj], 0, 0, 0);
    }

    // ---- k = 1, 2 ----
    for (int k = 1; k < Kx; ++k) {
        __syncthreads();   // k=1: (no-op hazard) ; k=2: big GEMM done reading sZk

        // small GEMM: Z_k[m][o] = Tm @ theta_k -> sZk[o][m]
        f32x4 accs[3][2];
#pragma unroll
        for (int j = 0; j < 3; ++j)
#pragma unroll
            for (int u = 0; u < 2; ++u) accs[j][u] = (f32x4)0.f;

#pragma unroll
        for (int s = 0; s < 2; ++s) {
            bf16x8 afr[3], bfr[2];
#pragma unroll
            for (int j = 0; j < 3; ++j)
                afr[j] = *(const bf16x8*)((const char*)sTm +
                         ((mg * 3 + j) * 16 + l16) * (TMW * 2) + s * 64 + lk * 16);
#pragma unroll
            for (int u = 0; u < 2; ++u)
                bfr[u] = *(const bf16x8*)(&g_thfrag[
                         ((((k * 2 + s) * 4) + og * 2 + u) * 64 + lane) * 8]);
#pragma unroll
            for (int j = 0; j < 3; ++j)
#pragma unroll
                for (int u = 0; u < 2; ++u)
                    accs[j][u] = __builtin_amdgcn_mfma_f32_16x16x32_bf16(afr[j], bfr[u], accs[j][u], 0, 0, 0);
        }
#pragma unroll
        for (int j = 0; j < 3; ++j)
#pragma unroll
            for (int u = 0; u < 2; ++u) {
                int o  = (og * 2 + u) * 16 + l16;
                int m0 = (mg * 3 + j) * 16 + lk * 4;
                bf16x4 v;
#pragma unroll
                for (int r = 0; r < 4; ++r) v[r] = f2bf(accs[j][u][r]);
                *(bf16x4*)((char*)sZk + o * (ZW * 2) + m0 * 2) = v;
            }
        __syncthreads();

        // big GEMM partial: GT[o][n] += Z_k^T[o][m] @ cheb_k[n][m]
#pragma unroll
        for (int s = 0; s < 6; ++s) {
            bf16x8 afr2[2], bfr2[3];
#pragma unroll
            for (int oi = 0; oi < 2; ++oi)
                afr2[oi] = *(const bf16x8*)((const char*)sZk +
                           ((wr * 2 + oi) * 16 + l16) * (ZW * 2) + s * 64 + lk * 16);
#pragma unroll
            for (int nj = 0; nj < 3; ++nj)
                bfr2[nj] = *(const bf16x8*)(&g_chebfrag[
                           ((((k * 6 + s) * 12) + wc * 3 + nj) * 64 + lane) * 8]);
#pragma unroll
            for (int oi = 0; oi < 2; ++oi)
#pragma unroll
                for (int nj = 0; nj < 3; ++nj)
                    accb[oi][nj] = __builtin_amdgcn_mfma_f32_16x16x32_bf16(afr2[oi], bfr2[nj], accb[oi][nj], 0, 0, 0);
        }
    }

    // ---- epilogue: relu + residual, scatter store ----
#pragma unroll
    for (int nj = 0; nj < 3; ++nj) {
        int n = (wc * 3 + nj) * 16 + l16;
        if (n < Nx) {
            float xf0 = sXs[n * XSW + 1];
            float xf1 = sXs[n * XSW + 4];
            float xf2 = sXs[n * XSW + 7];
#pragma unroll
            for (int oi = 0; oi < 2; ++oi) {
#pragma unroll
                for (int r = 0; r < 4; ++r) {
                    int o = (wr * 2 + oi) * 16 + lk * 4 + r;
                    float resv = sResB[o] + xf0 * sResW[o * 3 + 0]
                                          + xf1 * sResW[o * 3 + 1]
                                          + xf2 * sResW[o * 3 + 2];
                    out[((b * Ox + o) * Nx + n) * Tx + t0] =
                        fmaxf(accb[oi][nj][r], 0.f) + resv;
                }
            }
        }
    }
}

extern "C" void kernel_launch(void* const* d_in, const int* in_sizes, int n_in,
                              void* d_out, int out_size, void* d_ws, size_t ws_size,
                              hipStream_t stream) {
    const float* x      = (const float*)d_in[0];
    const float* cheb   = (const float*)d_in[2];
    const float* conv_w = (const float*)d_in[3];
    const float* conv_b = (const float*)d_in[4];
    const float* theta  = (const float*)d_in[5];
    const float* res_w  = (const float*)d_in[6];
    const float* res_b  = (const float*)d_in[7];
    float* out = (float*)d_out;

    int pre_elems = CHEBF_ELEMS + THF_ELEMS + WF_ELEMS;
    hipLaunchKernelGGL(precompute_frag, dim3((pre_elems + 511) / 512), dim3(512), 0, stream,
                       cheb, theta, conv_w, conv_b);
    hipLaunchKernelGGL(stgcn_fused5, dim3(NBT), dim3(512), 0, stream,
                       x, res_w, res_b, out);
}